// Round 14
// baseline (77.744 us; speedup 1.0000x reference)
//
#include <hip/hip_runtime.h>

// LinearAttention fp32 [4,16,4096,64]: out = (Q' (K'^T V)) / (Q'.k_sum + eps), X' = elu(X)+1.
// R14: kv pass re-tiled to NPB=64 (4096 blocks, 64 s-rows, 17KB LDS, 6 blocks/CU)
//   for smoother block-level streaming (was 2048 blocks @ 4/CU = 2 coarse
//   generations). Tiered: falls back to proven NPB=32 path if ws too small.
// Pass 1 (kv_mfma<NPB>): NT loads, single-phase, bf16 MFMA, partials -> ws.
// Pass 1b (reduce_partials<NPB>): float4 fold.
// Pass 2 (out_kernel): unchanged from R13 (MFMA, fp32 denom, barriered repack,
//   coalesced NT I/O).

#define EPS_LA 1e-6f

constexpr int BH = 64;
constexpr int SEQ = 4096;
constexpr int DIM = 64;
constexpr int KVELEM = DIM * DIM + DIM;  // 4160

typedef short bf16x8 __attribute__((ext_vector_type(8)));
typedef float f32x4 __attribute__((ext_vector_type(4)));

__device__ __forceinline__ float elu1(float x) {
    return x > 0.f ? x + 1.f : __expf(x);
}
__device__ __forceinline__ f32x4 elu4v(f32x4 v) {
    v[0] = elu1(v[0]); v[1] = elu1(v[1]); v[2] = elu1(v[2]); v[3] = elu1(v[3]);
    return v;
}
__device__ __forceinline__ f32x4 ntld(const float* p) {
    return __builtin_nontemporal_load((const f32x4*)p);
}

// fp32 -> bf16 (RNE; inputs finite)
__device__ __forceinline__ unsigned int f2bf(float x) {
    unsigned int u = __float_as_uint(x);
    return (u + 0x7fffu + ((u >> 16) & 1u)) >> 16;
}
__device__ __forceinline__ unsigned int pack2bf(float lo, float hi) {
    return f2bf(lo) | (f2bf(hi) << 16);
}

// LDS swizzle: dword index into [64 rows][S2N dword-cols]; XOR into s2 bits 2..4
// keeps 16B alignment; staging b32 writes ~2-way (free), b128 reads ~minimum.
template<int S2N>
__device__ __forceinline__ int swz(int d, int s2) {
    return d * S2N + (s2 ^ ((((d >> 1) ^ (d >> 2)) & 7) << 2));
}

template<int NPB, bool ATOMIC>
__global__ __launch_bounds__(256, (NPB == 64 ? 6 : 4)) void kv_mfma_kernel(
    const float* __restrict__ K, const float* __restrict__ V,
    float* __restrict__ dst) {
    constexpr int SCH = SEQ / NPB;   // s-rows per block: 64 (NPB=64) / 128 (32)
    constexpr int S2N = SCH / 2;     // s-pairs
    constexpr int NI = S2N / 16;     // per-thread pair iterations (2 / 4)
    constexpr int KS = SCH / 32;     // MFMA K-steps (2 / 4)

    const int bh = blockIdx.y;
    const int blk = blockIdx.x;
    const int t = threadIdx.x;
    const int w = t >> 6, l = t & 63;

    __shared__ unsigned int KT[64 * S2N];  // K'^T bf16 [d][s-pair] swizzled
    __shared__ unsigned int VT[64 * S2N];
    __shared__ float csumS[4][64];

    const float* Kb = K + ((size_t)bh * SEQ + (size_t)blk * SCH) * DIM;
    const float* Vb = V + ((size_t)bh * SEQ + (size_t)blk * SCH) * DIM;

    const int c0 = (t & 15) * 4;  // staged col base (d rows c0..c0+3)
    const int pg = t >> 4;        // s-pair group base: pairs pg + 16*i
    const int lg = l >> 4;        // MFMA k-slice group 0..3
    const int lr = l & 15;        // MFMA row/col within tile

    // ---- issue ALL non-temporal loads ----
    f32x4 kf[2 * NI], vf[2 * NI];
    #pragma unroll
    for (int i = 0; i < NI; ++i) {
        const int p = pg + 16 * i;
        kf[2 * i]     = ntld(Kb + (size_t)(2 * p) * DIM + c0);
        kf[2 * i + 1] = ntld(Kb + (size_t)(2 * p + 1) * DIM + c0);
    }
    #pragma unroll
    for (int i = 0; i < NI; ++i) {
        const int p = pg + 16 * i;
        vf[2 * i]     = ntld(Vb + (size_t)(2 * p) * DIM + c0);
        vf[2 * i + 1] = ntld(Vb + (size_t)(2 * p + 1) * DIM + c0);
    }

    // ---- elu + pack + transpose into LDS ----
    float cs0 = 0.f, cs1 = 0.f, cs2 = 0.f, cs3 = 0.f;
    #pragma unroll
    for (int i = 0; i < NI; ++i) {
        const int p = pg + 16 * i;
        const f32x4 ka = elu4v(kf[2 * i]);
        const f32x4 kb = elu4v(kf[2 * i + 1]);
        cs0 += ka[0] + kb[0]; cs1 += ka[1] + kb[1];
        cs2 += ka[2] + kb[2]; cs3 += ka[3] + kb[3];
        KT[swz<S2N>(c0 + 0, p)] = pack2bf(ka[0], kb[0]);
        KT[swz<S2N>(c0 + 1, p)] = pack2bf(ka[1], kb[1]);
        KT[swz<S2N>(c0 + 2, p)] = pack2bf(ka[2], kb[2]);
        KT[swz<S2N>(c0 + 3, p)] = pack2bf(ka[3], kb[3]);
        const f32x4 va = vf[2 * i], vb = vf[2 * i + 1];
        VT[swz<S2N>(c0 + 0, p)] = pack2bf(va[0], vb[0]);
        VT[swz<S2N>(c0 + 1, p)] = pack2bf(va[1], vb[1]);
        VT[swz<S2N>(c0 + 2, p)] = pack2bf(va[2], vb[2]);
        VT[swz<S2N>(c0 + 3, p)] = pack2bf(va[3], vb[3]);
    }

    // fold column sums across 16-lane groups (lanes l, l^16, l^32, l^48 share c0)
    cs0 += __shfl_xor(cs0, 16); cs0 += __shfl_xor(cs0, 32);
    cs1 += __shfl_xor(cs1, 16); cs1 += __shfl_xor(cs1, 32);
    cs2 += __shfl_xor(cs2, 16); cs2 += __shfl_xor(cs2, 32);
    cs3 += __shfl_xor(cs3, 16); cs3 += __shfl_xor(cs3, 32);
    if (l < 16) *(f32x4*)&csumS[w][l * 4] = f32x4{cs0, cs1, cs2, cs3};

    __syncthreads();  // the ONLY barrier

    // ---- MFMA: wave w owns e-cols [16w,16w+16); K=SCH in KS steps of 32 ----
    f32x4 acc[4];
    #pragma unroll
    for (int m = 0; m < 4; ++m)
        #pragma unroll
        for (int r = 0; r < 4; ++r) acc[m][r] = 0.f;

    #pragma unroll
    for (int ks = 0; ks < KS; ++ks) {
        const int s2b = ks * 16 + lg * 4;
        const bf16x8 bfrag =
            *reinterpret_cast<const bf16x8*>(&VT[swz<S2N>(16 * w + lr, s2b)]);
        #pragma unroll
        for (int m = 0; m < 4; ++m) {
            const bf16x8 afrag =
                *reinterpret_cast<const bf16x8*>(&KT[swz<S2N>(16 * m + lr, s2b)]);
            acc[m] = __builtin_amdgcn_mfma_f32_16x16x32_bf16(afrag, bfrag, acc[m],
                                                             0, 0, 0);
        }
    }

    float* wout = ATOMIC ? dst + (size_t)bh * KVELEM
                         : dst + ((size_t)blk * BH + bh) * KVELEM;

    if (t < 64) {
        const float s = csumS[0][t] + csumS[1][t] + csumS[2][t] + csumS[3][t];
        if (ATOMIC) atomicAdd(&wout[DIM * DIM + t], s);
        else        wout[DIM * DIM + t] = s;
    }

    #pragma unroll
    for (int m = 0; m < 4; ++m) {
        #pragma unroll
        for (int r = 0; r < 4; ++r) {
            const int d = 16 * m + 4 * lg + r;
            const int e = 16 * w + lr;
            if (ATOMIC) atomicAdd(&wout[(size_t)d * DIM + e], acc[m][r]);
            else        wout[(size_t)d * DIM + e] = acc[m][r];
        }
    }
}

template<int NPB>
__global__ __launch_bounds__(256) void reduce_partials_kernel(
    const float* __restrict__ partial, float* __restrict__ fin) {
    const int bh = blockIdx.y;
    const int j4 = blockIdx.x * 256 + threadIdx.x;  // float4 index (KVELEM/4 = 1040)
    if (j4 >= KVELEM / 4) return;
    f32x4 s = {0.f, 0.f, 0.f, 0.f};
    #pragma unroll
    for (int c = 0; c < NPB; ++c)
        s += *(const f32x4*)&partial[((size_t)c * BH + bh) * KVELEM + j4 * 4];
    *(f32x4*)&fin[(size_t)bh * KVELEM + j4 * 4] = s;
}

// Pass 2 (MFMA): block = 256 thr (4 waves); wave wv owns 32 q-rows.
// 2 m-tiles x 4 n-tiles x 2 k-steps = 16 MFMA; fp32 denom via shfl butterfly;
// acc repacked through per-wave LDS (barriered) -> coalesced NT f32x4 stores.
__global__ __launch_bounds__(256) void out_kernel(
    const float* __restrict__ Q, const float* __restrict__ ws,
    float* __restrict__ out) {
    const int bh = blockIdx.y;
    const int rb = blockIdx.x;  // 128-row block
    const int t = threadIdx.x;
    const int wv = t >> 6, l = t & 63;
    const int lr = l & 15, lg = l >> 4;

    __shared__ unsigned int qA[4 * 32 * 32];  // 16 KB: per-wave Q' bf16 [row][d-pair]
    __shared__ unsigned int kvT[64 * 32];     // 8 KB: kv^T bf16 [e][d-pair]
    __shared__ float denomS[128];

    const float* kvp = ws + (size_t)bh * KVELEM;
    const float* Qb = Q + ((size_t)bh * SEQ + (size_t)rb * 128) * DIM;
    float* Ob = out + ((size_t)bh * SEQ + (size_t)rb * 128) * DIM;

    // ---- kvT staging: kv[d][e] -> kvT[e][d-pairs] bf16, swizzled by (e&7) ----
    #pragma unroll
    for (int i = 0; i < 2; ++i) {
        const int p = (t >> 4) + 16 * i;     // d-pair 0..31
        const int e0 = (t & 15) * 4;
        const f32x4 a = *(const f32x4*)(kvp + (size_t)(2 * p) * DIM + e0);
        const f32x4 b = *(const f32x4*)(kvp + (size_t)(2 * p + 1) * DIM + e0);
        #pragma unroll
        for (int j = 0; j < 4; ++j) {
            const int e = e0 + j;
            kvT[e * 32 + (p ^ ((e & 7) << 2))] = pack2bf(a[j], b[j]);
        }
    }

    // ---- q staging (NT): elu, pack bf16, swizzle; fp32 denom partials ----
    const int c0 = lr * 4;
    const f32x4 ks4 = *(const f32x4*)(kvp + DIM * DIM + c0);  // fp32 ksum slice (hot)
    float pd[8];
    #pragma unroll
    for (int it = 0; it < 8; ++it) {
        const int row = it * 4 + lg;          // 0..31 within wave
        const f32x4 qv = elu4v(ntld(Qb + (size_t)(wv * 32 + row) * DIM + c0));
        pd[it] = qv[0] * ks4[0] + qv[1] * ks4[1] + qv[2] * ks4[2] + qv[3] * ks4[3];
        uint2 val;
        val.x = pack2bf(qv[0], qv[1]);
        val.y = pack2bf(qv[2], qv[3]);
        *(uint2*)&qA[wv * 1024 + row * 32 + ((2 * lr) ^ ((row & 7) << 2))] = val;
    }
    // butterfly over the 16-lane (lr) group -> full denom per row
    #pragma unroll
    for (int it = 0; it < 8; ++it) {
        float v = pd[it];
        v += __shfl_xor(v, 1); v += __shfl_xor(v, 2);
        v += __shfl_xor(v, 4); v += __shfl_xor(v, 8);
        if (lr == 0) denomS[wv * 32 + it * 4 + lg] = v + EPS_LA;
    }
    __syncthreads();

    // ---- MFMA: rows 16*mt+lr, cols 16*nt+lr, K=64 in 2 steps ----
    f32x4 acc[2][4];
    #pragma unroll
    for (int mt = 0; mt < 2; ++mt)
        #pragma unroll
        for (int nt = 0; nt < 4; ++nt)
            #pragma unroll
            for (int r = 0; r < 4; ++r) acc[mt][nt][r] = 0.f;

    #pragma unroll
    for (int ks = 0; ks < 2; ++ks) {
        const int kd = 4 * lg + 16 * ks;      // dword base of the lane's k-slice
        const int am = (lr & 7) << 2;
        const bf16x8 a0 = *(const bf16x8*)&qA[wv * 1024 + lr * 32 + (kd ^ am)];
        const bf16x8 a1 = *(const bf16x8*)&qA[wv * 1024 + (16 + lr) * 32 + (kd ^ am)];
        #pragma unroll
        for (int nt = 0; nt < 4; ++nt) {
            const bf16x8 b =
                *(const bf16x8*)&kvT[(16 * nt + lr) * 32 + (kd ^ am)];
            acc[0][nt] = __builtin_amdgcn_mfma_f32_16x16x32_bf16(a0, b, acc[0][nt],
                                                                 0, 0, 0);
            acc[1][nt] = __builtin_amdgcn_mfma_f32_16x16x32_bf16(a1, b, acc[1][nt],
                                                                 0, 0, 0);
        }
    }

    // ---- repack acc through per-wave LDS -> coalesced NT stores (barriered) ----
    float* oS = (float*)qA;  // per-wave 1024-float region at wv*1024
    #pragma unroll
    for (int mt = 0; mt < 2; ++mt) {
        __syncthreads();  // qA bf16 reads (mt=0) / prior read-back (mt=1) complete
        #pragma unroll
        for (int r = 0; r < 4; ++r) {
            const int row = 4 * lg + r;  // 0..15
            const float inv = 1.f / denomS[wv * 32 + mt * 16 + row];
            #pragma unroll
            for (int nt = 0; nt < 4; ++nt) {
                const int colp = (16 * nt + lr) ^ (lg << 4);
                oS[wv * 1024 + row * 64 + colp] = acc[mt][nt][r] * inv;
            }
        }
        __syncthreads();  // writes visible before read-back
        #pragma unroll
        for (int j = 0; j < 4; ++j) {
            const int row = 4 * j + lg;           // 0..15
            const int cb = lr * 4;
            const int colp = cb ^ ((row >> 2) << 4);
            const f32x4 o = *(const f32x4*)&oS[wv * 1024 + row * 64 + colp];
            float* orow = Ob + (size_t)(wv * 32 + mt * 16 + row) * DIM + cb;
            __builtin_nontemporal_store(o, (f32x4*)orow);
        }
    }
}

extern "C" void kernel_launch(void* const* d_in, const int* in_sizes, int n_in,
                              void* d_out, int out_size, void* d_ws, size_t ws_size,
                              hipStream_t stream) {
    const float* q = (const float*)d_in[0];
    const float* k = (const float*)d_in[1];
    const float* v = (const float*)d_in[2];
    float* out = (float*)d_out;
    float* ws = (float*)d_ws;

    const size_t need64 = (size_t)(64 + 1) * BH * KVELEM * sizeof(float);
    const size_t need32 = (size_t)(32 + 1) * BH * KVELEM * sizeof(float);

    dim3 blk(256);
    const float* fin_ptr;
    if (ws_size >= need64) {
        float* partial = ws;
        float* fin = ws + (size_t)64 * BH * KVELEM;
        hipLaunchKernelGGL((kv_mfma_kernel<64, false>), dim3(64, BH), blk, 0, stream,
                           k, v, partial);
        hipLaunchKernelGGL((reduce_partials_kernel<64>),
                           dim3((KVELEM / 4 + 255) / 256, BH), blk, 0, stream,
                           partial, fin);
        fin_ptr = fin;
    } else if (ws_size >= need32) {
        float* partial = ws;
        float* fin = ws + (size_t)32 * BH * KVELEM;
        hipLaunchKernelGGL((kv_mfma_kernel<32, false>), dim3(32, BH), blk, 0, stream,
                           k, v, partial);
        hipLaunchKernelGGL((reduce_partials_kernel<32>),
                           dim3((KVELEM / 4 + 255) / 256, BH), blk, 0, stream,
                           partial, fin);
        fin_ptr = fin;
    } else {
        float* fin = ws;
        hipMemsetAsync(fin, 0, (size_t)BH * KVELEM * sizeof(float), stream);
        hipLaunchKernelGGL((kv_mfma_kernel<32, true>), dim3(32, BH), blk, 0, stream,
                           k, v, fin);
        fin_ptr = fin;
    }
    hipLaunchKernelGGL(out_kernel, dim3(SEQ / 128, BH), blk, 0, stream,
                       q, fin_ptr, out);
}